// Round 6
// baseline (223.156 us; speedup 1.0000x reference)
//
#include <hip/hip_runtime.h>

#define IMG   256
#define IMG2  65536
#define NB    64
#define NB2   128

// Block-range layout (all blocks 256 threads), label FIRST so the compulsory
// HBM seg fetches start streaming at t=0 while cache-hot crops backfill:
//   [0, 2048)      label: b = t>>5, u0 = (t&31)*8  (8 rows; 2 rows/thread)
//   [2048, 4096)   crops S=8  (g=32): src = t>>5, ci = t&31
//   [4096, 5120)   crops S=16 (g=16): src = t>>4, ci = t&15
//   [5120, 5632)   crops S=32 (g=8):  src = t>>3, ci = t&7
#define NBLK_LBL  2048
#define NBLK_C8   2048
#define NBLK_C16  1024
#define NBLK_C32  512
#define NBLK_ALL  (NBLK_LBL + NBLK_C8 + NBLK_C16 + NBLK_C32)

// native clang vector type: __builtin_nontemporal_store rejects HIP's
// float4 class; this one it accepts.
typedef float vfloat4 __attribute__((ext_vector_type(4)));

__device__ __forceinline__ void nt_store4(float* p, float x, float y,
                                          float z, float w) {
    vfloat4 v = {x, y, z, w};
    __builtin_nontemporal_store(v, (vfloat4*)p);
}

// ---------------------------------------------------------------------------
// crops (register-resident, S=8/16): one block per (src, cell-row ci). Both
// the unshifted (A) and shifted (B) cells are contiguous S x S blocks at base
// max(c*S-4,0). One read sweep keeps all values in registers; min/max via
// shuffle + tiny-LDS reduce; normalize + nt float4 stores straight from regs.
// ---------------------------------------------------------------------------
template <int S>
__device__ __forceinline__ void crops_cell_row_reg(
    const float* __restrict__ img,
    const float* __restrict__ heat,
    float* __restrict__ out,
    int src, int ci,
    float (*s_red)[32][4],
    float (*s_fin)[4]) {
    constexpr int G   = IMG / S;
    constexpr int L   = (S == 8) ? 3 : 4;
    constexpr int CPL = S / 4;
    constexpr int K   = S / 4;

    const int tid = threadIdx.x;
    const int w   = tid >> 6;
    const int l   = tid & 63;
    const int cj  = l >> (L - 2);
    const int o   = (l & (CPL - 1)) * 4;

    const int rA   = ci * S;
    const int rB   = (ci == 0) ? 0 : rA - 4;
    const int colA = cj * S + o;
    const int colB = ((cj == 0) ? 0 : cj * S - 4) + o;

    const float* __restrict__ sp = img + (size_t)src * IMG2;

    float4 av[K], bv[K];
    float mnA = 3.4e38f, mxA = -3.4e38f, mnB = 3.4e38f, mxB = -3.4e38f;
#pragma unroll
    for (int k = 0; k < K; ++k) {
        const int r = w + 4 * k;
        av[k] = *(const float4*)(sp + (rA + r) * IMG + colA);
        bv[k] = *(const float4*)(sp + (rB + r) * IMG + colB);
    }
#pragma unroll
    for (int k = 0; k < K; ++k) {
        mnA = fminf(mnA, fminf(fminf(av[k].x, av[k].y), fminf(av[k].z, av[k].w)));
        mxA = fmaxf(mxA, fmaxf(fmaxf(av[k].x, av[k].y), fmaxf(av[k].z, av[k].w)));
        mnB = fminf(mnB, fminf(fminf(bv[k].x, bv[k].y), fminf(bv[k].z, bv[k].w)));
        mxB = fmaxf(mxB, fmaxf(fmaxf(bv[k].x, bv[k].y), fmaxf(bv[k].z, bv[k].w)));
    }
#pragma unroll
    for (int off = 1; off < CPL; off <<= 1) {
        mnA = fminf(mnA, __shfl_xor(mnA, off, 64));
        mxA = fmaxf(mxA, __shfl_xor(mxA, off, 64));
        mnB = fminf(mnB, __shfl_xor(mnB, off, 64));
        mxB = fmaxf(mxB, __shfl_xor(mxB, off, 64));
    }
    if ((l & (CPL - 1)) == 0) {
        float* p = &s_red[w][cj][0];
        p[0] = mnA; p[1] = mxA; p[2] = mnB; p[3] = mxB;
    }
    __syncthreads();
    if (tid < G) {
        float a0 = 3.4e38f, a1 = -3.4e38f, b0 = 3.4e38f, b1 = -3.4e38f;
#pragma unroll
        for (int ww = 0; ww < 4; ++ww) {
            a0 = fminf(a0, s_red[ww][tid][0]);
            a1 = fmaxf(a1, s_red[ww][tid][1]);
            b0 = fminf(b0, s_red[ww][tid][2]);
            b1 = fmaxf(b1, s_red[ww][tid][3]);
        }
        const float hA = heat[(size_t)src * G * G + ci * G + tid];
        const float hB = heat[(size_t)(src + NB) * G * G + ci * G + tid];
        s_fin[tid][0] = a0;
        s_fin[tid][1] = (hA > 0.5f ? 1.0f : 0.0f) / (a1 - a0 + 1e-5f);
        s_fin[tid][2] = b0;
        s_fin[tid][3] = (hB > 0.5f ? 1.0f : 0.0f) / (b1 - b0 + 1e-5f);
    }
    __syncthreads();
    const float fmnA = s_fin[cj][0], finvA = s_fin[cj][1];
    const float fmnB = s_fin[cj][2], finvB = s_fin[cj][3];

    float* __restrict__ dA = out + (size_t)src * IMG2;
    float* __restrict__ dB = out + (size_t)(src + NB) * IMG2;
#pragma unroll
    for (int k = 0; k < K; ++k) {
        const int r = w + 4 * k;
        nt_store4(dA + (rA + r) * IMG + colA,
                  (av[k].x - fmnA) * finvA, (av[k].y - fmnA) * finvA,
                  (av[k].z - fmnA) * finvA, (av[k].w - fmnA) * finvA);
        nt_store4(dB + (rA + r) * IMG + colA,
                  (bv[k].x - fmnB) * finvB, (bv[k].y - fmnB) * finvB,
                  (bv[k].z - fmnB) * finvB, (bv[k].w - fmnB) * finvB);
    }
}

// ---------------------------------------------------------------------------
// crops (two-sweep re-read, S=32 only): keeps kernel VGPR bounded; the second
// sweep re-reads from L1/L2 (img is fully cache-resident).
// ---------------------------------------------------------------------------
__device__ __forceinline__ void crops_cell_row_32(
    const float* __restrict__ img,
    const float* __restrict__ heat,
    float* __restrict__ out,
    int src, int ci,
    float (*s_red)[32][4],
    float (*s_fin)[4]) {
    constexpr int S = 32, G = 8, L = 5, CPL = 8;

    const int tid = threadIdx.x;
    const int w   = tid >> 6;
    const int l   = tid & 63;
    const int cj  = l >> (L - 2);
    const int o   = (l & (CPL - 1)) * 4;

    const int rA   = ci * S;
    const int rB   = (ci == 0) ? 0 : rA - 4;
    const int colA = cj * S + o;
    const int colB = ((cj == 0) ? 0 : cj * S - 4) + o;

    const float* __restrict__ sp = img + (size_t)src * IMG2;

    float mnA = 3.4e38f, mxA = -3.4e38f, mnB = 3.4e38f, mxB = -3.4e38f;
#pragma unroll
    for (int k = 0; k < S / 4; ++k) {
        const int r = w + 4 * k;
        const float4 a  = *(const float4*)(sp + (rA + r) * IMG + colA);
        const float4 bq = *(const float4*)(sp + (rB + r) * IMG + colB);
        mnA = fminf(mnA, fminf(fminf(a.x, a.y), fminf(a.z, a.w)));
        mxA = fmaxf(mxA, fmaxf(fmaxf(a.x, a.y), fmaxf(a.z, a.w)));
        mnB = fminf(mnB, fminf(fminf(bq.x, bq.y), fminf(bq.z, bq.w)));
        mxB = fmaxf(mxB, fmaxf(fmaxf(bq.x, bq.y), fmaxf(bq.z, bq.w)));
    }
#pragma unroll
    for (int off = 1; off < CPL; off <<= 1) {
        mnA = fminf(mnA, __shfl_xor(mnA, off, 64));
        mxA = fmaxf(mxA, __shfl_xor(mxA, off, 64));
        mnB = fminf(mnB, __shfl_xor(mnB, off, 64));
        mxB = fmaxf(mxB, __shfl_xor(mxB, off, 64));
    }
    if ((l & (CPL - 1)) == 0) {
        float* p = &s_red[w][cj][0];
        p[0] = mnA; p[1] = mxA; p[2] = mnB; p[3] = mxB;
    }
    __syncthreads();
    if (tid < G) {
        float a0 = 3.4e38f, a1 = -3.4e38f, b0 = 3.4e38f, b1 = -3.4e38f;
#pragma unroll
        for (int ww = 0; ww < 4; ++ww) {
            a0 = fminf(a0, s_red[ww][tid][0]);
            a1 = fmaxf(a1, s_red[ww][tid][1]);
            b0 = fminf(b0, s_red[ww][tid][2]);
            b1 = fmaxf(b1, s_red[ww][tid][3]);
        }
        const float hA = heat[(size_t)src * G * G + ci * G + tid];
        const float hB = heat[(size_t)(src + NB) * G * G + ci * G + tid];
        s_fin[tid][0] = a0;
        s_fin[tid][1] = (hA > 0.5f ? 1.0f : 0.0f) / (a1 - a0 + 1e-5f);
        s_fin[tid][2] = b0;
        s_fin[tid][3] = (hB > 0.5f ? 1.0f : 0.0f) / (b1 - b0 + 1e-5f);
    }
    __syncthreads();
    const float fmnA = s_fin[cj][0], finvA = s_fin[cj][1];
    const float fmnB = s_fin[cj][2], finvB = s_fin[cj][3];

    float* __restrict__ dA = out + (size_t)src * IMG2;
    float* __restrict__ dB = out + (size_t)(src + NB) * IMG2;
#pragma unroll
    for (int k = 0; k < S / 4; ++k) {
        const int r = w + 4 * k;
        const float4 a  = *(const float4*)(sp + (rA + r) * IMG + colA);
        const float4 bq = *(const float4*)(sp + (rB + r) * IMG + colB);
        nt_store4(dA + (rA + r) * IMG + colA,
                  (a.x - fmnA) * finvA, (a.y - fmnA) * finvA,
                  (a.z - fmnA) * finvA, (a.w - fmnA) * finvA);
        nt_store4(dB + (rA + r) * IMG + colA,
                  (bq.x - fmnB) * finvB, (bq.y - fmnB) * finvB,
                  (bq.z - fmnB) * finvB, (bq.w - fmnB) * finvB);
    }
}

// ---------------------------------------------------------------------------
// label: one row per (wave, slot); each thread handles TWO rows (u0+w and
// u0+4+w) at its 4-pixel column group -> 2x independent loads in flight.
// ---------------------------------------------------------------------------
template <bool FAST>
__device__ __forceinline__ void label_one_row(
    const float* __restrict__ heat8,
    const float* __restrict__ heat16,
    const float* __restrict__ heat32,
    const float* __restrict__ seg8,
    const float* __restrict__ seg16,
    const float* __restrict__ seg32,
    float* __restrict__ out,
    int b, int u, int v0, int vs) {
    float nu[4] = {0.f, 0.f, 0.f, 0.f};
    float de[4] = {0.f, 0.f, 0.f, 0.f};

    if constexpr (FAST) {
        const int i1 = u + 4;
#define SCALE_F(heat, seg, g, l, s)                                           \
        {                                                                     \
            const float* __restrict__ h1 = heat + b * (g * g);                \
            const float* __restrict__ h2 = heat + (NB + b) * (g * g);         \
            const float* __restrict__ r1 = seg + (size_t)b * IMG2 + u * IMG;  \
            const float* __restrict__ r2 =                                    \
                seg + (size_t)(NB + b) * IMG2 + i1 * IMG;                     \
            const float4 sd  = *(const float4*)(r1 + v0);                     \
            const float4 sg0 = *(const float4*)(r2 + v0);                     \
            const float4 sg1 = *(const float4*)(r2 + vs);                     \
            const float hd  = h1[(u >> l) * g + (v0 >> l)];                   \
            const float hg0 = h2[(i1 >> l) * g + (v0 >> l)];                  \
            const float hg1 = h2[(i1 >> l) * g + (vs >> l)];                  \
            const float md = (hd > 0.5f) ? 1.0f : 0.0f;                       \
            const float g0 = (hg0 > 0.5f) ? 1.0f : 0.0f;                      \
            const float g1 = (hg1 > 0.5f) ? 1.0f : 0.0f;                      \
            _Pragma("unroll")                                                 \
            for (int c = 0; c < 4; ++c) {                                     \
                const int v = v0 + c;                                         \
                const float m0 = (v < (s)) ? g0 : 0.0f;                       \
                const float m1 = (v >= (s) - 4 && v <= 251) ? g1 : 0.0f;      \
                float x = ((const float*)&sd)[c] * md;                        \
                x = fmaf(m0, ((const float*)&sg0)[c], x);                     \
                x = fmaf(m1, ((const float*)&sg1)[c], x);                     \
                nu[c] += x;                                                   \
                de[c] += md + m0 + m1;                                        \
            }                                                                 \
        }
        SCALE_F(heat32, seg32, 32, 3, 8)
        SCALE_F(heat16, seg16, 16, 4, 16)
        SCALE_F(heat8,  seg8,  8,  5, 32)
#undef SCALE_F
    } else {
        const int i0  = u;
        const int i1c = min(u + 4, 255);
#define SCALE_G(heat, seg, g, l, s)                                           \
        {                                                                     \
            const float* __restrict__ h1 = heat + b * (g * g);                \
            const float* __restrict__ h2 = heat + (NB + b) * (g * g);         \
            const float* __restrict__ r1 = seg + (size_t)b * IMG2 + u * IMG;  \
            const float* __restrict__ ra =                                    \
                seg + (size_t)(NB + b) * IMG2 + i0 * IMG;                     \
            const float* __restrict__ rb =                                    \
                seg + (size_t)(NB + b) * IMG2 + i1c * IMG;                    \
            const float4 sd  = *(const float4*)(r1 + v0);                     \
            const float4 a0q = *(const float4*)(ra + v0);                     \
            const float4 a1q = *(const float4*)(ra + vs);                     \
            const float4 b0q = *(const float4*)(rb + v0);                     \
            const float4 b1q = *(const float4*)(rb + vs);                     \
            const float hd  = h1[(u >> l) * g + (v0 >> l)];                   \
            const float hA0 = h2[(i0 >> l) * g + (v0 >> l)];                  \
            const float hA1 = h2[(i0 >> l) * g + (vs >> l)];                  \
            const float hB0 = h2[(i1c >> l) * g + (v0 >> l)];                 \
            const float hB1 = h2[(i1c >> l) * g + (vs >> l)];                 \
            const float miA = (u < (s)) ? 1.0f : 0.0f;                        \
            const float miB = (u >= (s) - 4 && u <= 251) ? 1.0f : 0.0f;       \
            const float md  = (hd > 0.5f) ? 1.0f : 0.0f;                      \
            const float gA0 = miA * ((hA0 > 0.5f) ? 1.0f : 0.0f);             \
            const float gA1 = miA * ((hA1 > 0.5f) ? 1.0f : 0.0f);             \
            const float gB0 = miB * ((hB0 > 0.5f) ? 1.0f : 0.0f);             \
            const float gB1 = miB * ((hB1 > 0.5f) ? 1.0f : 0.0f);             \
            _Pragma("unroll")                                                 \
            for (int c = 0; c < 4; ++c) {                                     \
                const int v = v0 + c;                                         \
                const float mj0 = (v < (s)) ? 1.0f : 0.0f;                    \
                const float mj1 = (v >= (s) - 4 && v <= 251) ? 1.0f : 0.0f;   \
                const float w00 = gA0 * mj0, w01 = gA1 * mj1;                 \
                const float w10 = gB0 * mj0, w11 = gB1 * mj1;                 \
                float x = ((const float*)&sd)[c] * md;                        \
                x = fmaf(w00, ((const float*)&a0q)[c], x);                    \
                x = fmaf(w01, ((const float*)&a1q)[c], x);                    \
                x = fmaf(w10, ((const float*)&b0q)[c], x);                    \
                x = fmaf(w11, ((const float*)&b1q)[c], x);                    \
                nu[c] += x;                                                   \
                de[c] += md + w00 + w01 + w10 + w11;                          \
            }                                                                 \
        }
        SCALE_G(heat32, seg32, 32, 3, 8)
        SCALE_G(heat16, seg16, 16, 4, 16)
        SCALE_G(heat8,  seg8,  8,  5, 32)
#undef SCALE_G
    }

    nt_store4(out + (size_t)b * IMG2 + u * IMG + v0,
              nu[0] / (de[0] + 1e-10f), nu[1] / (de[1] + 1e-10f),
              nu[2] / (de[2] + 1e-10f), nu[3] / (de[3] + 1e-10f));
}

__device__ __forceinline__ void label_rows8(
    const float* __restrict__ heat8,
    const float* __restrict__ heat16,
    const float* __restrict__ heat32,
    const float* __restrict__ seg8,
    const float* __restrict__ seg16,
    const float* __restrict__ seg32,
    float* __restrict__ out,
    int b, int u0) {
    const int wave = threadIdx.x >> 6;
    const int lane = threadIdx.x & 63;
    const int v0   = lane << 2;
    const int vs   = min(v0 + 4, 252);
    const int uA   = u0 + wave;
    const int uB   = u0 + 4 + wave;

    // fast iff all 8 rows in [32,251]: u0 (mult of 8) in [32,240]
    if (u0 >= 32 && u0 <= 240) {
        label_one_row<true>(heat8, heat16, heat32, seg8, seg16, seg32, out,
                            b, uA, v0, vs);
        label_one_row<true>(heat8, heat16, heat32, seg8, seg16, seg32, out,
                            b, uB, v0, vs);
    } else {
        label_one_row<false>(heat8, heat16, heat32, seg8, seg16, seg32, out,
                             b, uA, v0, vs);
        label_one_row<false>(heat8, heat16, heat32, seg8, seg16, seg32, out,
                             b, uB, v0, vs);
    }
}

__global__ __launch_bounds__(256) void fused_kernel(
    const float* __restrict__ img,
    const float* __restrict__ heat8,
    const float* __restrict__ heat16,
    const float* __restrict__ heat32,
    const float* __restrict__ seg8,
    const float* __restrict__ seg16,
    const float* __restrict__ seg32,
    float* __restrict__ out) {
    __shared__ float s_red[4][32][4];
    __shared__ float s_fin[32][4];

    float* crops32 = out;                           // (128,1,256,256) s=8
    float* crops16 = out + (size_t)NB2 * IMG2;      // s=16
    float* crops8  = out + (size_t)2 * NB2 * IMG2;  // s=32
    float* label   = out + (size_t)3 * NB2 * IMG2;  // (64,1,256,256)

    const int bid = blockIdx.x;
    if (bid < NBLK_LBL) {
        label_rows8(heat8, heat16, heat32, seg8, seg16, seg32, label,
                    bid >> 5, (bid & 31) << 3);
    } else if (bid < NBLK_LBL + NBLK_C8) {
        const int t = bid - NBLK_LBL;
        crops_cell_row_reg<8>(img, heat32, crops32, t >> 5, t & 31, s_red, s_fin);
    } else if (bid < NBLK_LBL + NBLK_C8 + NBLK_C16) {
        const int t = bid - (NBLK_LBL + NBLK_C8);
        crops_cell_row_reg<16>(img, heat16, crops16, t >> 4, t & 15, s_red, s_fin);
    } else {
        const int t = bid - (NBLK_LBL + NBLK_C8 + NBLK_C16);
        crops_cell_row_32(img, heat8, crops8, t >> 3, t & 7, s_red, s_fin);
    }
}

extern "C" void kernel_launch(void* const* d_in, const int* in_sizes, int n_in,
                              void* d_out, int out_size, void* d_ws, size_t ws_size,
                              hipStream_t stream) {
    const float* img    = (const float*)d_in[0];
    const float* heat8  = (const float*)d_in[1];
    const float* heat16 = (const float*)d_in[2];
    const float* heat32 = (const float*)d_in[3];
    const float* seg8   = (const float*)d_in[4];
    const float* seg16  = (const float*)d_in[5];
    const float* seg32  = (const float*)d_in[6];

    fused_kernel<<<dim3(NBLK_ALL), 256, 0, stream>>>(
        img, heat8, heat16, heat32, seg8, seg16, seg32, (float*)d_out);
}